// Round 11
// baseline (612.502 us; speedup 1.0000x reference)
//
#include <hip/hip_runtime.h>
#include <cstddef>

static constexpr int kN = 4096;
static constexpr int kF = 512;
static constexpr int kH = 256;
static constexpr float kClamp = 1e-6f;

using bf16x8 = __attribute__((ext_vector_type(8))) __bf16;
using f32x4 = __attribute__((ext_vector_type(4))) float;
using ushort8 = __attribute__((ext_vector_type(8))) unsigned short;
using ushort4v = __attribute__((ext_vector_type(4))) unsigned short;

static constexpr size_t PLANE_XF = (size_t)kN * kF;      // 2.1M
static constexpr size_t PLANE_NN = (size_t)kN * kN;      // 16.8M
static constexpr size_t PLANE_W = (size_t)512 * 512;
static constexpr size_t PLANE_W1 = (size_t)256 * 512;
static constexpr size_t PLANE_V0 = (size_t)1024 * kN;
static constexpr size_t PLANE_H = (size_t)kN * 1024;
static constexpr size_t PLANE_V1 = (size_t)512 * kN;

__device__ __forceinline__ unsigned short f2bf(float x) {
  unsigned int u = __float_as_uint(x);
  u += 0x7fffu + ((u >> 16) & 1u);
  return (unsigned short)(u >> 16);
}
__device__ __forceinline__ float bf2f(unsigned short h) {
  return __uint_as_float(((unsigned int)h) << 16);
}
__device__ __forceinline__ void split3(float x, unsigned short& h,
                                       unsigned short& m, unsigned short& l) {
  h = f2bf(x);
  const float r1 = x - bf2f(h);
  m = f2bf(r1);
  l = f2bf(r1 - bf2f(m));
}
__device__ __forceinline__ void split2(float x, unsigned short& h,
                                       unsigned short& m) {
  h = f2bf(x);
  m = f2bf(x - bf2f(h));
}
__device__ __forceinline__ void split2x4(const float4 v, ushort4v& h4,
                                         ushort4v& m4) {
  unsigned short h, m;
  split2(v.x, h, m); h4.x = h; m4.x = m;
  split2(v.y, h, m); h4.y = h; m4.y = m;
  split2(v.z, h, m); h4.z = h; m4.z = m;
  split2(v.w, h, m); h4.w = h; m4.w = m;
}

__device__ __forceinline__ bf16x8 ldfrag(const unsigned short* p) {
  ushort8 r = *(const ushort8*)p;
  return __builtin_bit_cast(bf16x8, r);
}
__device__ __forceinline__ f32x4 mfma16(bf16x8 a, bf16x8 b, f32x4 c) {
  return __builtin_amdgcn_mfma_f32_16x16x32_bf16(a, b, c, 0, 0, 0);
}
// 6-product (split3): rel err ~2^-26
__device__ __forceinline__ f32x4 mfma_split6(const bf16x8* a3, const bf16x8* b3,
                                             f32x4 acc) {
  acc = mfma16(a3[2], b3[0], acc);
  acc = mfma16(a3[0], b3[2], acc);
  acc = mfma16(a3[1], b3[1], acc);
  acc = mfma16(a3[1], b3[0], acc);
  acc = mfma16(a3[0], b3[1], acc);
  acc = mfma16(a3[0], b3[0], acc);
  return acc;
}

// async global->LDS, 16B per lane; lds ptr must be wave-uniform (HW adds lane*16)
__device__ __forceinline__ void gload16(const unsigned short* g,
                                        unsigned short* l) {
  __builtin_amdgcn_global_load_lds(
      (const __attribute__((address_space(1))) void*)g,
      (__attribute__((address_space(3))) void*)l, 16, 0, 0);
}

__device__ __forceinline__ void tri_map(int b, int& bi, int& bj) {
  int x = (int)((sqrtf(8.0f * (float)b + 1.0f) - 1.0f) * 0.5f);
  while ((x + 1) * (x + 2) / 2 <= b) ++x;
  while (x * (x + 1) / 2 > b) --x;
  bi = x;
  bj = b - x * (x + 1) / 2;
}

__device__ __forceinline__ float block_reduce_sum(float v, float* sbuf) {
  const int tid = threadIdx.x;
  sbuf[tid] = v;
  __syncthreads();
#pragma unroll
  for (int s = 128; s > 0; s >>= 1) {
    if (tid < s) sbuf[tid] += sbuf[tid + s];
    __syncthreads();
  }
  const float r = sbuf[0];
  __syncthreads();
  return r;
}

// ============ prep: transpose+split weights ============
__global__ __launch_bounds__(256) void prep_w(
    const float* s0, const float* s1, const float* s2, const float* s3,
    const float* s4, const float* s5, unsigned short* d0, unsigned short* d1,
    unsigned short* d2, unsigned short* d3, unsigned short* d4,
    unsigned short* d5) {
  const int seg = blockIdx.y;
  const float* src;
  unsigned short* dst;
  int N;
  bool tri;
  switch (seg) {
    case 0: src = s0; dst = d0; N = 512; tri = true; break;
    case 1: src = s1; dst = d1; N = 512; tri = true; break;
    case 2: src = s2; dst = d2; N = 512; tri = false; break;
    case 3: src = s3; dst = d3; N = 512; tri = false; break;
    case 4: src = s4; dst = d4; N = 256; tri = false; break;
    default: src = s5; dst = d5; N = 256; tri = false; break;
  }
  const int id = blockIdx.x * 256 + threadIdx.x;
  if (id >= 512 * N) return;
  const int k = id & 511;
  const int n = id >> 9;
  const float v = src[(size_t)k * N + n];
  const size_t base = (size_t)n * 512 + k;
  const size_t plane = (size_t)512 * N;
  if (tri) {
    unsigned short h, m, l;
    split3(v, h, m, l);
    dst[base] = h;
    dst[plane + base] = m;
    dst[2 * plane + base] = l;
  } else {
    unsigned short h, m;
    split2(v, h, m);
    dst[base] = h;
    dst[plane + base] = m;
  }
}

// ============ split x into 3 planes ============
__global__ __launch_bounds__(256) void split_x(const float* __restrict__ x,
                                               unsigned short* __restrict__ x3) {
  const size_t id = (size_t)blockIdx.x * 256 + threadIdx.x;
  unsigned short h, m, l;
  split3(x[id], h, m, l);
  x3[id] = h;
  x3[PLANE_XF + id] = m;
  x3[2 * PLANE_XF + id] = l;
}

// ============ GEMM-1 (split3, 6-product): x@Wm|Ws -> XMf|XSf (f32) ============
// DMA-staged (r9 pattern): LDS linear [3][rows][32el], global_load_lds,
// (row>>1)&3 slot involution.
__global__ __launch_bounds__(256) void gemm_x(
    const unsigned short* __restrict__ A3, const unsigned short* __restrict__ B30,
    const unsigned short* __restrict__ B31, float* __restrict__ C0,
    float* __restrict__ C1, const float* __restrict__ bias0,
    const float* __restrict__ bias1) {
  constexpr int BM = 128, BN = 64, K = 512;
  __shared__ __align__(16) unsigned short Asl[3][BM][32];  // 24 KiB
  __shared__ __align__(16) unsigned short Bsl[3][BN][32];  // 12 KiB
  const int tid = threadIdx.x;
  const int lane = tid & 63;
  const int wave = tid >> 6;
  const int wm = wave >> 1, wn = wave & 1;
  const int m0 = blockIdx.y * BM;
  const int n0 = blockIdx.x * BN;
  const bool str1 = (n0 >= 512);
  const int nloc = str1 ? (n0 - 512) : n0;
  const unsigned short* Bb = str1 ? B31 : B30;
  const float* bias = str1 ? bias1 : bias0;
  float* C = str1 ? C1 : C0;
  const int rl = lane & 15;
  const int kq = (lane >> 4) * 8;
  const int q = lane >> 4;
  const int kqs = kq ^ (((rl >> 1) & 3) << 3);
  const int sslot = (((lane & 3) ^ ((lane >> 3) & 3)) * 8);

  f32x4 acc[4][2];
#pragma unroll
  for (int i = 0; i < 4; ++i)
#pragma unroll
    for (int j = 0; j < 2; ++j) acc[i][j] = (f32x4){0.f, 0.f, 0.f, 0.f};

  for (int k0 = 0; k0 < K; k0 += 32) {
    // A: 24 chunks (3 planes x 8 rowblocks); B: 12 chunks (3 x 4). 1 KiB each.
#pragma unroll
    for (int it = 0; it < 9; ++it) {
      const int c = it * 4 + wave;
      if (c < 24) {
        const int plane = c >> 3;
        const int row = (c & 7) * 16 + (lane >> 2);
        gload16(&A3[(size_t)plane * PLANE_XF + (size_t)(m0 + row) * K + k0 +
                    sslot],
                &Asl[0][0][0] + c * 512);
      } else {
        const int cl = c - 24;
        const int plane = cl >> 2;
        const int row = (cl & 3) * 16 + (lane >> 2);
        gload16(&Bb[(size_t)plane * PLANE_W + (size_t)(nloc + row) * K + k0 +
                    sslot],
                &Bsl[0][0][0] + cl * 512);
      }
    }
    __syncthreads();  // drains vmcnt -> DMA landed
    bf16x8 af[4][3], bfr[2][3];
#pragma unroll
    for (int mt = 0; mt < 4; ++mt)
#pragma unroll
      for (int t = 0; t < 3; ++t)
        af[mt][t] = ldfrag(&Asl[t][wm * 64 + mt * 16 + rl][kqs]);
#pragma unroll
    for (int nt = 0; nt < 2; ++nt)
#pragma unroll
      for (int t = 0; t < 3; ++t)
        bfr[nt][t] = ldfrag(&Bsl[t][wn * 32 + nt * 16 + rl][kqs]);
#pragma unroll
    for (int mt = 0; mt < 4; ++mt)
#pragma unroll
      for (int nt = 0; nt < 2; ++nt)
        acc[mt][nt] = mfma_split6(af[mt], bfr[nt], acc[mt][nt]);
    __syncthreads();
  }
#pragma unroll
  for (int mt = 0; mt < 4; ++mt)
#pragma unroll
    for (int nt = 0; nt < 2; ++nt) {
      const int col = nloc + wn * 32 + nt * 16 + rl;
      const int row0 = m0 + wm * 64 + mt * 16 + q * 4;
      const float bv = bias[col];
#pragma unroll
      for (int r = 0; r < 4; ++r)
        C[(size_t)(row0 + r) * 512 + col] = acc[mt][nt][r] + bv;
    }
}

// ============ split2 3-product GEMM, CT-split2 output (small GEMMs) ============
// DMA-staged (r9 pattern).
template <int BM, int BN>
__global__ __launch_bounds__(256) void gemm2ct(
    const unsigned short* __restrict__ A0, const unsigned short* __restrict__ A1,
    int lda, size_t planeA, const unsigned short* __restrict__ B0,
    const unsigned short* __restrict__ B1, int ldb, size_t planeB,
    unsigned short* __restrict__ Cs0, unsigned short* __restrict__ Cs1, int ldc,
    size_t planeC, int N1, int K, const float* __restrict__ rowScale) {
  __shared__ __align__(16) unsigned short Asl[2][BM][32];
  __shared__ __align__(16) unsigned short Bsl[2][BN][32];
  const int tid = threadIdx.x;
  const int lane = tid & 63;
  const int wave = tid >> 6;
  const int wm = wave >> 1, wn = wave & 1;
  const int m0 = blockIdx.y * BM;
  const int n0 = blockIdx.x * BN;
  const bool str1 = (n0 >= N1);
  const int nloc = str1 ? (n0 - N1) : n0;
  const unsigned short* Ab = str1 ? A1 : A0;
  const unsigned short* Bb = str1 ? B1 : B0;
  const int rl = lane & 15;
  const int kq = (lane >> 4) * 8;
  const int q = lane >> 4;
  const int kqs = kq ^ (((rl >> 1) & 3) << 3);
  const int sslot = (((lane & 3) ^ ((lane >> 3) & 3)) * 8);
  constexpr int MT = BM / 32;
  constexpr int NT = BN / 32;
  constexpr int ACH = 2 * (BM / 16);
  constexpr int BCH = 2 * (BN / 16);
  constexpr int TCH = ACH + BCH;
  static_assert(TCH % 4 == 0, "chunk count must be divisible by 4 waves");

  f32x4 acc[MT][NT];
#pragma unroll
  for (int i = 0; i < MT; ++i)
#pragma unroll
    for (int j = 0; j < NT; ++j) acc[i][j] = (f32x4){0.f, 0.f, 0.f, 0.f};

  for (int k0 = 0; k0 < K; k0 += 32) {
#pragma unroll
    for (int it = 0; it < TCH / 4; ++it) {
      const int c = it * 4 + wave;
      if (c < ACH) {
        const int plane = c / (BM / 16);
        const int row = (c % (BM / 16)) * 16 + (lane >> 2);
        gload16(&Ab[(size_t)plane * planeA + (size_t)(m0 + row) * lda + k0 +
                    sslot],
                &Asl[0][0][0] + c * 512);
      } else {
        const int cl = c - ACH;
        const int plane = cl / (BN / 16);
        const int row = (cl % (BN / 16)) * 16 + (lane >> 2);
        gload16(&Bb[(size_t)plane * planeB + (size_t)(nloc + row) * ldb + k0 +
                    sslot],
                &Bsl[0][0][0] + cl * 512);
      }
    }
    __syncthreads();  // drains vmcnt -> DMA landed
    bf16x8 af[MT][2];
#pragma unroll
    for (int mt = 0; mt < MT; ++mt)
#pragma unroll
      for (int t = 0; t < 2; ++t)
        af[mt][t] = ldfrag(&Asl[t][wm * (BM / 2) + mt * 16 + rl][kqs]);
#pragma unroll
    for (int nt = 0; nt < NT; ++nt) {
      const bf16x8 b0 = ldfrag(&Bsl[0][wn * (BN / 2) + nt * 16 + rl][kqs]);
      const bf16x8 b1 = ldfrag(&Bsl[1][wn * (BN / 2) + nt * 16 + rl][kqs]);
#pragma unroll
      for (int mt = 0; mt < MT; ++mt) {
        acc[mt][nt] = mfma16(af[mt][1], b0, acc[mt][nt]);
        acc[mt][nt] = mfma16(af[mt][0], b1, acc[mt][nt]);
        acc[mt][nt] = mfma16(af[mt][0], b0, acc[mt][nt]);
      }
    }
    __syncthreads();
  }

#pragma unroll
  for (int mt = 0; mt < MT; ++mt) {
#pragma unroll
    for (int nt = 0; nt < NT; ++nt) {
      const int colL = nloc + wn * (BN / 2) + nt * 16 + rl;
      const int row0 = m0 + wm * (BM / 2) + mt * 16 + q * 4;
      float4 v4;
      float* vp = &v4.x;
#pragma unroll
      for (int r = 0; r < 4; ++r) {
        float v = acc[mt][nt][r];
        if (rowScale) v *= rowScale[row0 + r];
        vp[r] = v;
      }
      unsigned short* C = str1 ? Cs1 : Cs0;
      ushort4v h4, m4;
      split2x4(v4, h4, m4);
      const size_t base = (size_t)colL * ldc + row0;
      *(ushort4v*)(&C[base]) = h4;
      *(ushort4v*)(&C[planeC + base]) = m4;
    }
  }
}

// ============ split2 3-product GEMM, split-K, XCD-swizzled, DMA-staged =======
// m97-structure 2-barrier schedule; 0 bank conflicts (r6). ~860 TF plateau.
template <int BM, int BN, int GX, int GYP, int GZ>
__global__ __launch_bounds__(256) void gemm2k(
    const unsigned short* __restrict__ A, int lda, size_t planeA,
    const unsigned short* __restrict__ B, int ldb, size_t planeB,
    float* __restrict__ Cp, int ldc, int Mtot, int Ksl) {
  static_assert(BM == 128 && BN == 128, "DMA staging assumes 128x128");
  __shared__ __align__(16) unsigned short Asl[2][BM][32];  // 16 KiB
  __shared__ __align__(16) unsigned short Bsl[2][BN][32];  // 16 KiB
  const int lin = blockIdx.x;
  const int xcd = lin & 7;
  const int s = lin >> 3;
  constexpr int per = GX * GYP;
  const int z = s / per;
  const int r = s - z * per;
  const int bx = r % GX;
  const int by = xcd * GYP + r / GX;
  const int m0 = by * BM;
  const int n0 = bx * BN;
  const int kOff = z * Ksl;

  const int tid = threadIdx.x;
  const int lane = tid & 63;
  const int wave = tid >> 6;
  const int wm = wave >> 1, wn = wave & 1;
  const int rl = lane & 15;
  const int kq = (lane >> 4) * 8;
  const int q = lane >> 4;
  const int kqs = kq ^ (((rl >> 1) & 3) << 3);
  const int sslot = (((lane & 3) ^ ((lane >> 3) & 3)) * 8);
  constexpr int MT = BM / 32;
  constexpr int NT = BN / 32;

  f32x4 acc[MT][NT];
#pragma unroll
  for (int i = 0; i < MT; ++i)
#pragma unroll
    for (int j = 0; j < NT; ++j) acc[i][j] = (f32x4){0.f, 0.f, 0.f, 0.f};

  for (int k0 = 0; k0 < Ksl; k0 += 32) {
#pragma unroll
    for (int it = 0; it < 8; ++it) {
      const int c = it * 4 + wave;
      const bool isB = c >= 16;
      const int cl = isB ? (c - 16) : c;
      const int pl = cl >> 3;
      const int row = (cl & 7) * 16 + (lane >> 2);
      const unsigned short* src =
          (isB ? B + (size_t)pl * planeB + (size_t)(n0 + row) * ldb
               : A + (size_t)pl * planeA + (size_t)(m0 + row) * lda) +
          kOff + k0 + sslot;
      unsigned short* dst =
          (isB ? &Bsl[0][0][0] : &Asl[0][0][0]) + cl * 512 + 0;
      gload16(src, dst);
    }
    __syncthreads();  // drains vmcnt -> DMA landed
    bf16x8 af[MT][2];
#pragma unroll
    for (int mt = 0; mt < MT; ++mt)
#pragma unroll
      for (int t = 0; t < 2; ++t)
        af[mt][t] = ldfrag(&Asl[t][wm * (BM / 2) + mt * 16 + rl][kqs]);
#pragma unroll
    for (int nt = 0; nt < NT; ++nt) {
      const bf16x8 b0 = ldfrag(&Bsl[0][wn * (BN / 2) + nt * 16 + rl][kqs]);
      const bf16x8 b1 = ldfrag(&Bsl[1][wn * (BN / 2) + nt * 16 + rl][kqs]);
#pragma unroll
      for (int mt = 0; mt < MT; ++mt) {
        acc[mt][nt] = mfma16(af[mt][1], b0, acc[mt][nt]);
        acc[mt][nt] = mfma16(af[mt][0], b1, acc[mt][nt]);
        acc[mt][nt] = mfma16(af[mt][0], b0, acc[mt][nt]);
      }
    }
    __syncthreads();  // protect single buffer before next DMA
  }

  const size_t zoff = (size_t)z * (size_t)Mtot * (size_t)ldc;
#pragma unroll
  for (int mt = 0; mt < MT; ++mt) {
#pragma unroll
    for (int nt = 0; nt < NT; ++nt) {
      const int colL = n0 + wn * (BN / 2) + nt * 16 + rl;
      const int row0 = m0 + wm * (BM / 2) + mt * 16 + q * 4;
#pragma unroll
      for (int r2 = 0; r2 < 4; ++r2)
        Cp[zoff + (size_t)(row0 + r2) * ldc + colL] = acc[mt][nt][r2];
    }
  }
}

// ============ 8-phase pipelined split2 3-product GEMM (256x256, BK=32) =======
// r4/r5 structure (verified correct twice), with the CORRECT T2 swizzle this
// time: r4 had none (8-way read conflict), r5 used (row&3) which still leaves
// 4-way among same-parity rows. Correct involution (r6/r9-proven, 0 conflicts):
//   read slot: kq ^ 8*((row>>1)&3);  global src slot: (tid&3)^((tid>>3)&3).
// T3+T4+T5: dbuf 128 KiB LDS, global_load_lds, raw s_barrier, counted
// vmcnt(7) once per K-tile, setprio around MFMA clusters.
#define GK8_READ_A(P, AF)                                                   \
  {                                                                         \
    _Pragma("unroll") for (int e = 0; e < 2; ++e)                           \
        _Pragma("unroll") for (int pl = 0; pl < 2; ++pl)                    \
            AF[e][pl] = ldfrag(&Abuf[cur][P][pl][wm][e * 16 + rl][kqs]);    \
  }
#define GK8_MFMA(P, AF)                                                     \
  {                                                                         \
    _Pragma("unroll") for (int e = 0; e < 2; ++e)                           \
        _Pragma("unroll") for (int nt = 0; nt < 4; ++nt) {                  \
      acc[2 * (P) + e][nt] =                                                \
          mfma16(AF[e][1], bfr[nt][0], acc[2 * (P) + e][nt]);               \
      acc[2 * (P) + e][nt] =                                                \
          mfma16(AF[e][0], bfr[nt][1], acc[2 * (P) + e][nt]);               \
      acc[2 * (P) + e][nt] =                                                \
          mfma16(AF[e][0], bfr[nt][0], acc[2 * (P) + e][nt]);               \
    }                                                                       \
  }

template <int GX, int GYP, int GZ>
__global__ __launch_bounds__(512, 2) void gemm2k8(
    const unsigned short* __restrict__ A, int lda, size_t planeA,
    const unsigned short* __restrict__ B, int ldb, size_t planeB,
    float* __restrict__ Cp, int ldc, int Mtot, int Ksl) {
  __shared__ __align__(16) unsigned short Abuf[2][4][2][2][32][32];  // 64 KiB
  __shared__ __align__(16) unsigned short Bbuf[2][2][256][32];       // 64 KiB
  const int lin = blockIdx.x;
  const int xcd = lin & 7;
  const int s = lin >> 3;
  constexpr int per = GX * GYP;
  const int z = s / per;
  const int r = s - z * per;
  const int bx = r % GX;
  const int by = xcd * GYP + r / GX;
  const int m0 = by * 256;
  const int n0 = bx * 256;
  const int kOff = z * Ksl;
  const int ntk = Ksl >> 5;

  const int tid = threadIdx.x;
  const int lane = tid & 63;
  const int wave = tid >> 6;  // 0..7
  const int wm = wave >> 2;   // 0..1
  const int wn = wave & 3;    // 0..3
  const int rl = lane & 15;
  const int kq = (lane >> 4) * 8;
  const int q = lane >> 4;
  // CORRECT T2 swizzle (r6/r9 involution): spreads same-parity rows.
  const int kqs = kq ^ (((rl >> 1) & 3) << 3);

  // staging: thread tid -> row (tid>>2), LDS slot (tid&3) (linear dst);
  // global src slot = (tid&3) ^ ((row>>1)&3) = (tid&3) ^ ((tid>>3)&3).
  const int stRow = tid >> 2;        // B chunk: row within 128-row block
  const int stSlot = (((tid & 3) ^ ((tid >> 3) & 3)) * 8);
  const int aPl = tid >> 8;
  const int aHalf = (tid >> 7) & 1;
  const int aR = (tid >> 2) & 31;

  auto stageB = [&](int bi, int kt, int c) {
    const unsigned short* src = B + (size_t)(c >> 1) * planeB +
                                (size_t)(n0 + (c & 1) * 128 + stRow) * ldb +
                                kOff + kt * 32 + stSlot;
    unsigned short* dst = &Bbuf[bi][0][0][0] + c * 4096 + wave * 512;
    gload16(src, dst);
  };
  auto stageA = [&](int bi, int kt, int p) {
    const unsigned short* src =
        A + (size_t)aPl * planeA +
        (size_t)(m0 + aHalf * 128 + p * 32 + aR) * lda + kOff + kt * 32 +
        stSlot;
    unsigned short* dst = &Abuf[bi][0][0][0][0][0] + p * 4096 + wave * 512;
    gload16(src, dst);
  };

  f32x4 acc[8][4];
#pragma unroll
  for (int i = 0; i < 8; ++i)
#pragma unroll
    for (int j = 0; j < 4; ++j) acc[i][j] = (f32x4){0.f, 0.f, 0.f, 0.f};

  // prologue: tile 0 -> buf0 (8 loads), tile 1 -> buf1 (8 loads)
#pragma unroll
  for (int c = 0; c < 4; ++c) stageB(0, 0, c);
#pragma unroll
  for (int p = 0; p < 4; ++p) stageA(0, 0, p);
#pragma unroll
  for (int c = 0; c < 4; ++c) stageB(1, 1, c);
#pragma unroll
  for (int p = 0; p < 4; ++p) stageA(1, 1, p);
  asm volatile("s_waitcnt vmcnt(8)" ::: "memory");  // tile0 landed
  __builtin_amdgcn_s_barrier();

  for (int t = 0; t < ntk; ++t) {
    const int cur = t & 1;
    const bool refill = (t + 2 < ntk);
    // ---------- phase 0 ----------
    if (t >= 1 && t + 1 < ntk) stageA(cur ^ 1, t + 1, 3);  // deferred G7
    bf16x8 bfr[4][2];
#pragma unroll
    for (int nt = 0; nt < 4; ++nt)
#pragma unroll
      for (int pl = 0; pl < 2; ++pl)
        bfr[nt][pl] = ldfrag(&Bbuf[cur][pl][wn * 64 + nt * 16 + rl][kqs]);
    bf16x8 af0[2][2];
    GK8_READ_A(0, af0);
    __builtin_amdgcn_s_barrier();
    __builtin_amdgcn_s_setprio(1);
    GK8_MFMA(0, af0);
    __builtin_amdgcn_s_setprio(0);
    __builtin_amdgcn_s_barrier();
    // ---------- phase 1 ----------
    if (refill) {
      stageB(cur, t + 2, 0);
      stageB(cur, t + 2, 1);
      stageB(cur, t + 2, 2);
      stageB(cur, t + 2, 3);
      stageA(cur, t + 2, 0);
    }
    bf16x8 af1[2][2];
    GK8_READ_A(1, af1);
    __builtin_amdgcn_s_barrier();
    __builtin_amdgcn_s_setprio(1);
    GK8_MFMA(1, af1);
    __builtin_amdgcn_s_setprio(0);
    __builtin_amdgcn_s_barrier();
    // ---------- phase 2 ----------
    if (refill) stageA(cur, t + 2, 1);
    bf16x8 af2[2][2];
    GK8_READ_A(2, af2);
    __builtin_amdgcn_s_barrier();
    __builtin_amdgcn_s_setprio(1);
    GK8_MFMA(2, af2);
    __builtin_amdgcn_s_setprio(0);
    __builtin_amdgcn_s_barrier();
    // ---------- phase 3 ----------
    if (refill) stageA(cur, t + 2, 2);
    bf16x8 af3[2][2];
    GK8_READ_A(3, af3);
    __builtin_amdgcn_s_barrier();
    __builtin_amdgcn_s_setprio(1);
    GK8_MFMA(3, af3);
    __builtin_amdgcn_s_setprio(0);
    if (refill) {
      asm volatile("s_waitcnt vmcnt(7)" ::: "memory");
    } else {
      asm volatile("s_waitcnt vmcnt(0)" ::: "memory");
    }
    __builtin_amdgcn_s_barrier();
  }

  const size_t zoff = (size_t)z * (size_t)Mtot * (size_t)ldc;
#pragma unroll
  for (int mt = 0; mt < 8; ++mt) {
#pragma unroll
    for (int nt = 0; nt < 4; ++nt) {
      const int col = n0 + wn * 64 + nt * 16 + rl;
      const int row0 = m0 + wm * 128 + mt * 16 + q * 4;
#pragma unroll
      for (int r2 = 0; r2 < 4; ++r2)
        Cp[zoff + (size_t)(row0 + r2) * ldc + col] = acc[mt][nt][r2];
    }
  }
}

// ============ row stats: XMf/XSf f32 -> M2/CS2/XM2/XS2 planes ============
__global__ __launch_bounds__(256) void row_stats(
    const float* __restrict__ XMf, const float* __restrict__ XSf,
    unsigned short* __restrict__ M2, unsigned short* __restrict__ CS2,
    unsigned short* __restrict__ XM2, unsigned short* __restrict__ XS2,
    float* __restrict__ sq, float* __restrict__ csum) {
  __shared__ float sbuf[256];
  const int i = blockIdx.x;
  const int tid = threadIdx.x;
  const size_t base = (size_t)i * kF;
  const size_t i0 = base + tid, i1 = base + tid + 256;
  const float x0 = XMf[i0], x1 = XMf[i1];
  {
    unsigned short h, m;
    split2(x0, h, m);
    XM2[i0] = h; XM2[PLANE_XF + i0] = m;
    split2(x1, h, m);
    XM2[i1] = h; XM2[PLANE_XF + i1] = m;
  }
  const float nrm = block_reduce_sum(x0 * x0 + x1 * x1, sbuf);
  const float inv = 1.0f / fmaxf(sqrtf(nrm), 1e-12f);
  const float m0 = x0 * inv, m1 = x1 * inv;
  {
    unsigned short h, m;
    split2(m0, h, m);
    M2[i0] = h; M2[PLANE_XF + i0] = m;
    split2(m1, h, m);
    M2[i1] = h; M2[PLANE_XF + i1] = m;
  }
  const float s2 = block_reduce_sum(m0 * m0 + m1 * m1, sbuf);
  if (tid == 0) sq[i] = s2;

  const float y0 = XSf[i0], y1 = XSf[i1];
  {
    unsigned short h, m;
    split2(y0, h, m);
    XS2[i0] = h; XS2[PLANE_XF + i0] = m;
    split2(y1, h, m);
    XS2[i1] = h; XS2[PLANE_XF + i1] = m;
  }
  const float e0 = expf(y0), e1 = expf(y1);
  const float nrm2 = block_reduce_sum(e0 * e0 + e1 * e1, sbuf);
  const float inv2 = 1.0f / fmaxf(sqrtf(nrm2), 1e-12f);
  const float c0 = e0 * inv2, c1 = e1 * inv2;
  const float sc = block_reduce_sum(c0 + c1, sbuf);
  if (tid == 0) csum[i] = sc;
  {
    unsigned short h, m;
    split2(sqrtf(c0), h, m);
    CS2[i0] = h; CS2[PLANE_XF + i0] = m;
    split2(sqrtf(c1), h, m);
    CS2[i1] = h; CS2[PLANE_XF + i1] = m;
  }
}

// ============ symmetric dual NT-GEMM (split2, 3-prod): ws_raw = exp(-res) ====
// 128x128 tri-tiles, DMA-staged, 64 KiB LDS (2 blocks/CU). Frozen (r9 win).
__global__ __launch_bounds__(256, 2) void ws_mfma2(
    const unsigned short* __restrict__ M2, const unsigned short* __restrict__ CS2,
    const float* __restrict__ sq, const float* __restrict__ csum,
    float* __restrict__ WSR) {
  __shared__ __align__(16) unsigned short S[4][2][128][32];  // 64 KiB
  int bi, bj;
  tri_map(blockIdx.x, bi, bj);
  const int i0 = bi * 128, j0 = bj * 128;
  const int tid = threadIdx.x;
  const int lane = tid & 63;
  const int wave = tid >> 6;
  const int wm = wave >> 1, wn = wave & 1;
  const int rl = lane & 15;
  const int kq = (lane >> 4) * 8;
  const int q = lane >> 4;
  const int kqs = kq ^ (((rl >> 1) & 3) << 3);
  const int sslot = (((lane & 3) ^ ((lane >> 3) & 3)) * 8);

  f32x4 aM[4][4], aC[4][4];
#pragma unroll
  for (int i = 0; i < 4; ++i)
#pragma unroll
    for (int j = 0; j < 4; ++j) {
      aM[i][j] = (f32x4){0.f, 0.f, 0.f, 0.f};
      aC[i][j] = (f32x4){0.f, 0.f, 0.f, 0.f};
    }

  for (int k0 = 0; k0 < kF; k0 += 32) {
#pragma unroll
    for (int it = 0; it < 16; ++it) {
      const int c = it * 4 + wave;
      const int op = c >> 4;
      const int plane = (c >> 3) & 1;
      const int row = (c & 7) * 16 + (lane >> 2);
      const unsigned short* mat = (op & 1) ? CS2 : M2;
      const int rowoff = (op < 2) ? i0 : j0;
      const unsigned short* src = mat + (size_t)plane * PLANE_XF +
                                  (size_t)(rowoff + row) * kF + k0 + sslot;
      unsigned short* dst = &S[0][0][0][0] + c * 512;
      gload16(src, dst);
    }
    __syncthreads();  // drains vmcnt -> DMA landed
    bf16x8 am[4][2], ac[4][2];
#pragma unroll
    for (int mt = 0; mt < 4; ++mt)
#pragma unroll
      for (int t = 0; t < 2; ++t) {
        am[mt][t] = ldfrag(&S[0][t][wm * 64 + mt * 16 + rl][kqs]);
        ac[mt][t] = ldfrag(&S[1][t][wm * 64 + mt * 16 + rl][kqs]);
      }
#pragma unroll
    for (int nt = 0; nt < 4; ++nt) {
      const bf16x8 bm0 = ldfrag(&S[2][0][wn * 64 + nt * 16 + rl][kqs]);
      const bf16x8 bm1 = ldfrag(&S[2][1][wn * 64 + nt * 16 + rl][kqs]);
      const bf16x8 bc0 = ldfrag(&S[3][0][wn * 64 + nt * 16 + rl][kqs]);
      const bf16x8 bc1 = ldfrag(&S[3][1][wn * 64 + nt * 16 + rl][kqs]);
#pragma unroll
      for (int mt = 0; mt < 4; ++mt) {
        aM[mt][nt] = mfma16(am[mt][1], bm0, aM[mt][nt]);
        aM[mt][nt] = mfma16(am[mt][0], bm1, aM[mt][nt]);
        aM[mt][nt] = mfma16(am[mt][0], bm0, aM[mt][nt]);
        aC[mt][nt] = mfma16(ac[mt][1], bc0, aC[mt][nt]);
        aC[mt][nt] = mfma16(ac[mt][0], bc1, aC[mt][nt]);
        aC[mt][nt] = mfma16(ac[mt][0], bc0, aC[mt][nt]);
      }
    }
    __syncthreads();
  }

#pragma unroll
  for (int mt = 0; mt < 4; ++mt) {
#pragma unroll
    for (int nt = 0; nt < 4; ++nt) {
      const int j = j0 + wn * 64 + nt * 16 + rl;
      const int ib = i0 + wm * 64 + mt * 16 + q * 4;
      const float sqj = sq[j], csj = csum[j];
      float4 vv;
      float* vp = &vv.x;
#pragma unroll
      for (int r = 0; r < 4; ++r) {
        const int i = ib + r;
        const float d2 = fmaxf(sq[i] + sqj - 2.0f * aM[mt][nt][r], 0.0f);
        const float res = d2 + csum[i] + csj - 2.0f * aC[mt][nt][r];
        const float v = expf(-res);
        vp[r] = v;
        WSR[(size_t)i * kN + j] = v;
      }
      if (bi != bj) *(float4*)(&WSR[(size_t)j * kN + ib]) = vv;
    }
  }
}

// ============ row inverse L2 norm of WSR ============
__global__ __launch_bounds__(256) void row_invnorm_kernel(
    const float* __restrict__ WSR, float* __restrict__ invn) {
  __shared__ float sbuf[256];
  const int i = blockIdx.x;
  const int tid = threadIdx.x;
  const float4* rp = (const float4*)(WSR + (size_t)i * kN);
  float s = 0.0f;
#pragma unroll
  for (int q = 0; q < (kN / 4) / 256; ++q) {
    const float4 v = rp[tid + q * 256];
    s += v.x * v.x + v.y * v.y + v.z * v.z + v.w * v.w;
  }
  s = block_reduce_sum(s, sbuf);
  if (tid == 0) invn[i] = 1.0f / fmaxf(sqrtf(s), 1e-12f);
}

// ============ adjacency transform + transposed 2-plane split + deg ============
__device__ __forceinline__ float adj_val(float w, float inv, float nev, float ev,
                                         float b, float d, bool diag) {
  float t = (1.0f - b) * (w * inv) + b * nev;
  t = fminf(fmaxf(t, kClamp), 1.0f - kClamp);
  const float e = fminf(fmaxf(ev, kClamp), 1.0f - kClamp);
  const float num = t * e;
  const float den = num + (1.0f - t) * (1.0f - e);
  const float s = num / den;
  float v = (s > d) ? s : 0.0f;
  if (diag) v = (v > 0.0f) ? v : 1.0f;
  return v;
}

__global__ __launch_bounds__(256) void adj_transpose(
    const float* __restrict__ WSR, const float* __restrict__ invn,
    const float* __restrict__ ne, const float* __restrict__ epsm,
    const float* __restrict__ beta_p, const float* __restrict__ delta_p,
    unsigned short* __restrict__ Adj2, float* __restrict__ degp) {
  __shared__ float T0[64][65];
  __shared__ float T1[64][65];
  const float b = beta_p[0];
  const float d = delta_p[0];
  int bi, bj;
  tri_map(blockIdx.x, bi, bj);
  const int i0 = bi * 64, j0 = bj * 64;
  const int tid = threadIdx.x;
  const int rlq = tid >> 4;
  const int cq = (tid & 15) * 4;
#pragma unroll
  for (int p = 0; p < 4; ++p) {
    const int ii = p * 16 + rlq;
    {
      const size_t off = (size_t)(i0 + ii) * kN + j0 + cq;
      const float4 w4 = *(const float4*)(&WSR[off]);
      const float4 n4 = *(const float4*)(&ne[off]);
      const float4 e4 = *(const float4*)(&epsm[off]);
      const float inv = invn[i0 + ii];
      const float wv[4] = {w4.x, w4.y, w4.z, w4.w};
      const float nv[4] = {n4.x, n4.y, n4.z, n4.w};
      const float ev[4] = {e4.x, e4.y, e4.z, e4.w};
#pragma unroll
      for (int u = 0; u < 4; ++u)
        T0[ii][cq + u] =
            adj_val(wv[u], inv, nv[u], ev[u], b, d, (i0 + ii) == (j0 + cq + u));
    }
    if (bi != bj) {
      const size_t off = (size_t)(j0 + ii) * kN + i0 + cq;
      const float4 w4 = *(const float4*)(&WSR[off]);
      const float4 n4 = *(const float4*)(&ne[off]);
      const float4 e4 = *(const float4*)(&epsm[off]);
      const float inv = invn[j0 + ii];
      const float wv[4] = {w4.x, w4.y, w4.z, w4.w};
      const float nv[4] = {n4.x, n4.y, n4.z, n4.w};
      const float ev[4] = {e4.x, e4.y, e4.z, e4.w};
#pragma unroll
      for (int u = 0; u < 4; ++u)
        T1[ii][cq + u] = adj_val(wv[u], inv, nv[u], ev[u], b, d, false);
    }
  }
  __syncthreads();
#pragma unroll
  for (int p = 0; p < 4; ++p) {
    const int jj = p * 16 + rlq;
    {
      const float4 v4 = make_float4(T0[cq + 0][jj], T0[cq + 1][jj],
                                    T0[cq + 2][jj], T0[cq + 3][jj]);
      ushort4v h4, m4;
      split2x4(v4, h4, m4);
      const size_t base = (size_t)(j0 + jj) * kN + i0 + cq;
      *(ushort4v*)(&Adj2[base]) = h4;
      *(ushort4v*)(&Adj2[PLANE_NN + base]) = m4;
    }
    if (bi != bj) {
      const float4 v4 = make_float4(T1[cq + 0][jj], T1[cq + 1][jj],
                                    T1[cq + 2][jj], T1[cq + 3][jj]);
      ushort4v h4, m4;
      split2x4(v4, h4, m4);
      const size_t base = (size_t)(i0 + jj) * kN + j0 + cq;
      *(ushort4v*)(&Adj2[base]) = h4;
      *(ushort4v*)(&Adj2[PLANE_NN + base]) = m4;
    }
  }
  if (tid < 64) {
    float s = 0.0f;
#pragma unroll 8
    for (int ii = 0; ii < 64; ++ii) s += T0[ii][tid];
    degp[(size_t)bi * kN + j0 + tid] = s;
    if (bi != bj) {
      float s1 = 0.0f;
#pragma unroll 8
      for (int ii = 0; ii < 64; ++ii) s1 += T1[ii][tid];
      degp[(size_t)bj * kN + i0 + tid] = s1;
    }
  }
}

__global__ __launch_bounds__(256) void deg_dis_kernel(
    const float* __restrict__ degp, float* __restrict__ dis) {
  const int j = blockIdx.x * 256 + threadIdx.x;
  float s = 0.0f;
#pragma unroll
  for (int c = 0; c < 64; ++c) s += degp[(size_t)c * kN + j];
  dis[j] = (s > 0.0f) ? (1.0f / sqrtf(s)) : 0.0f;
}

// ============ split-K combines ============
__global__ __launch_bounds__(256) void combine_h(
    const float* __restrict__ hp, const float* __restrict__ dis,
    const float* __restrict__ b0, const float* __restrict__ b1,
    unsigned short* __restrict__ h2) {
  const size_t qd = (size_t)blockIdx.x * 256 + threadIdx.x;
  const int m = (int)(qd >> 8);
  const int c0 = (int)(qd & 255) * 4;
  const size_t off = (size_t)m * 1024 + c0;
  const float4 s0 = *(const float4*)(&hp[off]);
  const float4 s1 = *(const float4*)(&hp[PLANE_H + off]);
  const float4 s2 = *(const float4*)(&hp[2 * PLANE_H + off]);
  const float4 s3 = *(const float4*)(&hp[3 * PLANE_H + off]);
  const float4 bv = (c0 < 512) ? *(const float4*)(&b0[c0])
                               : *(const float4*)(&b1[c0 - 512]);
  const float ds = dis[m];
  float4 v4;
  v4.x = fmaxf(ds * (s0.x + s1.x + s2.x + s3.x) + bv.x, 0.f);
  v4.y = fmaxf(ds * (s0.y + s1.y + s2.y + s3.y) + bv.y, 0.f);
  v4.z = fmaxf(ds * (s0.z + s1.z + s2.z + s3.z) + bv.z, 0.f);
  v4.w = fmaxf(ds * (s0.w + s1.w + s2.w + s3.w) + bv.w, 0.f);
  ushort4v h4, m4;
  split2x4(v4, h4, m4);
  *(ushort4v*)(&h2[off]) = h4;
  *(ushort4v*)(&h2[PLANE_H + off]) = m4;
}

__global__ __launch_bounds__(256) void combine_z(
    const float* __restrict__ zp, const float* __restrict__ dis,
    const float* __restrict__ b0, const float* __restrict__ b1,
    float* __restrict__ out) {
  const size_t qd = (size_t)blockIdx.x * 256 + threadIdx.x;
  const int m = (int)(qd >> 7);
  const int c0 = (int)(qd & 127) * 4;
  const size_t off = (size_t)m * 512 + c0;
  constexpr size_t PZ = (size_t)kN * 512;
  const float4 s0 = *(const float4*)(&zp[off]);
  const float4 s1 = *(const float4*)(&zp[PZ + off]);
  const float4 s2 = *(const float4*)(&zp[2 * PZ + off]);
  const float4 s3 = *(const float4*)(&zp[3 * PZ + off]);
  const float4 bv = (c0 < 256) ? *(const float4*)(&b0[c0])
                               : *(const float4*)(&b1[c0 - 256]);
  const float ds = dis[m];
  float4 v4;
  v4.x = fmaxf(ds * (s0.x + s1.x + s2.x + s3.x) + bv.x, 0.f);
  v4.y = fmaxf(ds * (s0.y + s1.y + s2.y + s3.y) + bv.y, 0.f);
  v4.z = fmaxf(ds * (s0.z + s1.z + s2.z + s3.z) + bv.z, 0.f);
  v4.w = fmaxf(ds * (s0.w + s1.w + s2.w + s3.w) + bv.w, 0.f);
  float* dst = (c0 < 256) ? &out[(size_t)m * 256 + c0]
                          : &out[(size_t)kN * 256 + (size_t)m * 256 + (c0 - 256)];
  *(float4*)dst = v4;
}

// ============ launch ============
extern "C" void kernel_launch(void* const* d_in, const int* in_sizes, int n_in,
                              void* d_out, int out_size, void* d_ws,
                              size_t ws_size, hipStream_t stream) {
  const float* x = (const float*)d_in[0];
  const float* ne = (const float*)d_in[1];
  const float* beta = (const float*)d_in[2];
  const float* delta = (const float*)d_in[3];
  const float* epsm = (const float*)d_in[4];
  const float* Wm = (const float*)d_in[5];
  const float* bm = (const float*)d_in[6];
  const float* Ws = (const float*)d_in[7];
  const float* bs = (const float*)d_in[8];
  const float* mW0 = (const float*)d_in[9];
  const float* mb0 = (const float*)d_in[10];
  const float* mW1 = (const float*)d_in[11];
  const float* mb1 = (const float*)d_in[12];
  const float* sW0 = (const float*)d_in[13];
  const float* sb0 = (const float*)d_in[14];
  const float* sW1 = (const float*)d_in[15];
  const float* sb1 = (const float*)d_in[16];
  float* out = (float*)d_out;

  // WSR (67.1 MB) is dead after adj_transpose; hp/zp (<= 67.1 MB) alias it.
  char* p = (char*)d_ws;
  float* WSR = (float*)p;                     p += PLANE_NN * 4;
  unsigned short* Adj2 = (unsigned short*)p;  p += 2 * PLANE_NN * 2;
  unsigned short* x3 = (unsigned short*)p;    p += 3 * PLANE_XF * 2;  // -> V1t2
  float* XMf = (float*)p;                     p += PLANE_XF * 4;
  float* XSf = (float*)p;                     p += PLANE_XF * 4;
  unsigned short* XM2 = (unsigned short*)p;   p += 2 * PLANE_XF * 2;  // -> h2
  unsigned short* XS2 = (unsigned short*)p;   p += 2 * PLANE_XF * 2;
  unsigned short* M2 = (unsigned short*)p;    p += 2 * PLANE_XF * 2;  // -> V0t2
  unsigned short* CS2 = (unsigned short*)p;   p += 2 * PLANE_XF * 2;
  unsigned short* Wm3 = (unsigned short*)p;   p += 3 * PLANE_W * 2;
  unsigned short* Ws3 = (unsigned short*)p;   p += 3 * PLANE_W * 2;
  unsigned short* mW0t2 = (unsigned short*)p; p += 2 * PLANE_W * 2;
  unsigned short* sW0t2 = (unsigned short*)p; p += 2 * PLANE_W * 2;
  unsigned short* mW1t2 = (unsigned short*)p; p += 2 * PLANE_W1 * 2;
  unsigned short* sW1t2 = (unsigned short*)p; p += 2 * PLANE_W1 * 2;
  float* degp = (float*)p;                    p += (size_t)64 * kN * 4;
  float* sq = (float*)p;                      p += kN * 4;
  float* csum = (float*)p;                    p += kN * 4;
  float* invn = (float*)p;                    p += kN * 4;
  float* dis = (float*)p;                     p += kN * 4;

  float* hp = WSR;   // 4 * PLANE_H floats = PLANE_NN floats exactly
  float* zp = WSR;   // 4 * kN*512 floats = PLANE_NN/2 floats
  unsigned short* V1t2 = x3;
  unsigned short* h2 = XM2;
  unsigned short* V0t2 = M2;

  const dim3 blk(256);
  const int nTri = (kN / 64) * (kN / 64 + 1) / 2;       // 2080 (64-tiles)
  const int nTri128 = (kN / 128) * (kN / 128 + 1) / 2;  // 528 (128-tiles)

  prep_w<<<dim3(1024, 6), blk, 0, stream>>>(Wm, Ws, mW0, sW0, mW1, sW1, Wm3,
                                            Ws3, mW0t2, sW0t2, mW1t2, sW1t2);
  split_x<<<(kN * kF) / 256, blk, 0, stream>>>(x, x3);

  // 1) x_mean/x_std (split3, full precision) -> f32, DMA-staged
  gemm_x<<<dim3(16, 32), blk, 0, stream>>>(x3, Wm3, Ws3, XMf, XSf, bm, bs);

  // 2) row stats + all split2 planes
  row_stats<<<kN, blk, 0, stream>>>(XMf, XSf, M2, CS2, XM2, XS2, sq, csum);

  // 3) ws_raw (triangle + mirror), 128x128 DMA-staged tiles
  ws_mfma2<<<nTri128, blk, 0, stream>>>(M2, CS2, sq, csum, WSR);

  // 4) row inverse norms
  row_invnorm_kernel<<<kN, blk, 0, stream>>>(WSR, invn);

  // 5) adjacency -> Adj2 (transposed 2-plane) + deg partials. WSR dead after.
  adj_transpose<<<nTri, blk, 0, stream>>>(WSR, invn, ne, epsm, beta, delta,
                                          Adj2, degp);
  deg_dis_kernel<<<kN / 256, blk, 0, stream>>>(degp, dis);

  // 6) V0t = (dis_i * XM@W0 | XS@W0)^T  -> split2 CT planes [1024][4096]
  gemm2ct<128, 64><<<dim3(16, 32), blk, 0, stream>>>(
      XM2, XS2, kF, PLANE_XF, mW0t2, sW0t2, kF, PLANE_W, V0t2,
      V0t2 + (size_t)512 * kN, kN, PLANE_V0, 512, kF, dis);

  // 7) h partials: AdjT @ V0t, 8-phase (correct T2 swizzle), split-K=4
  //    (8*4*2*4 = 256 blocks of 512 thr)
  gemm2k8<4, 2, 4><<<256, dim3(512), 0, stream>>>(
      Adj2, kN, PLANE_NN, V0t2, kN, PLANE_V0, hp, 1024, kN, kN / 4);
  combine_h<<<(int)(PLANE_H / 4 / 256), blk, 0, stream>>>(hp, dis, mb0, sb0, h2);

  // 8) V1t = (dis_i * h@W1)^T -> split2 CT planes [512][4096]
  gemm2ct<64, 64><<<dim3(8, 64), blk, 0, stream>>>(
      h2, h2 + 512, 1024, PLANE_H, mW1t2, sW1t2, kF, PLANE_W1, V1t2,
      V1t2 + (size_t)256 * kN, kN, PLANE_V1, 256, kF, dis);

  // 9) z partials: AdjT @ V1t, 2-barrier gemm2k (control arm), split-K=4
  gemm2k<128, 128, 4, 4, 4><<<512, blk, 0, stream>>>(
      Adj2, kN, PLANE_NN, V1t2, kN, PLANE_V1, zp, 512, kN, kN / 4);
  combine_z<<<(int)((size_t)kN * 512 / 4 / 256), blk, 0, stream>>>(zp, dis, mb1,
                                                                   sb1, out);
}

// Round 12
// 600.507 us; speedup vs baseline: 1.0200x; 1.0200x over previous
//
#include <hip/hip_runtime.h>
#include <cstddef>

static constexpr int kN = 4096;
static constexpr int kF = 512;
static constexpr int kH = 256;
static constexpr float kClamp = 1e-6f;

using bf16x8 = __attribute__((ext_vector_type(8))) __bf16;
using f32x4 = __attribute__((ext_vector_type(4))) float;
using ushort8 = __attribute__((ext_vector_type(8))) unsigned short;
using ushort4v = __attribute__((ext_vector_type(4))) unsigned short;

static constexpr size_t PLANE_XF = (size_t)kN * kF;      // 2.1M
static constexpr size_t PLANE_NN = (size_t)kN * kN;      // 16.8M
static constexpr size_t PLANE_W = (size_t)512 * 512;
static constexpr size_t PLANE_W1 = (size_t)256 * 512;
static constexpr size_t PLANE_V0 = (size_t)1024 * kN;
static constexpr size_t PLANE_H = (size_t)kN * 1024;
static constexpr size_t PLANE_V1 = (size_t)512 * kN;

__device__ __forceinline__ unsigned short f2bf(float x) {
  unsigned int u = __float_as_uint(x);
  u += 0x7fffu + ((u >> 16) & 1u);
  return (unsigned short)(u >> 16);
}
__device__ __forceinline__ float bf2f(unsigned short h) {
  return __uint_as_float(((unsigned int)h) << 16);
}
__device__ __forceinline__ void split3(float x, unsigned short& h,
                                       unsigned short& m, unsigned short& l) {
  h = f2bf(x);
  const float r1 = x - bf2f(h);
  m = f2bf(r1);
  l = f2bf(r1 - bf2f(m));
}
__device__ __forceinline__ void split2(float x, unsigned short& h,
                                       unsigned short& m) {
  h = f2bf(x);
  m = f2bf(x - bf2f(h));
}
__device__ __forceinline__ void split2x4(const float4 v, ushort4v& h4,
                                         ushort4v& m4) {
  unsigned short h, m;
  split2(v.x, h, m); h4.x = h; m4.x = m;
  split2(v.y, h, m); h4.y = h; m4.y = m;
  split2(v.z, h, m); h4.z = h; m4.z = m;
  split2(v.w, h, m); h4.w = h; m4.w = m;
}

__device__ __forceinline__ bf16x8 ldfrag(const unsigned short* p) {
  ushort8 r = *(const ushort8*)p;
  return __builtin_bit_cast(bf16x8, r);
}
__device__ __forceinline__ f32x4 mfma16(bf16x8 a, bf16x8 b, f32x4 c) {
  return __builtin_amdgcn_mfma_f32_16x16x32_bf16(a, b, c, 0, 0, 0);
}
// 6-product (split3): rel err ~2^-26
__device__ __forceinline__ f32x4 mfma_split6(const bf16x8* a3, const bf16x8* b3,
                                             f32x4 acc) {
  acc = mfma16(a3[2], b3[0], acc);
  acc = mfma16(a3[0], b3[2], acc);
  acc = mfma16(a3[1], b3[1], acc);
  acc = mfma16(a3[1], b3[0], acc);
  acc = mfma16(a3[0], b3[1], acc);
  acc = mfma16(a3[0], b3[0], acc);
  return acc;
}

// async global->LDS, 16B per lane; lds ptr must be wave-uniform (HW adds lane*16)
__device__ __forceinline__ void gload16(const unsigned short* g,
                                        unsigned short* l) {
  __builtin_amdgcn_global_load_lds(
      (const __attribute__((address_space(1))) void*)g,
      (__attribute__((address_space(3))) void*)l, 16, 0, 0);
}

__device__ __forceinline__ void tri_map(int b, int& bi, int& bj) {
  int x = (int)((sqrtf(8.0f * (float)b + 1.0f) - 1.0f) * 0.5f);
  while ((x + 1) * (x + 2) / 2 <= b) ++x;
  while (x * (x + 1) / 2 > b) --x;
  bi = x;
  bj = b - x * (x + 1) / 2;
}

__device__ __forceinline__ float block_reduce_sum(float v, float* sbuf) {
  const int tid = threadIdx.x;
  sbuf[tid] = v;
  __syncthreads();
#pragma unroll
  for (int s = 128; s > 0; s >>= 1) {
    if (tid < s) sbuf[tid] += sbuf[tid + s];
    __syncthreads();
  }
  const float r = sbuf[0];
  __syncthreads();
  return r;
}

// ============ prep: transpose+split weights ============
__global__ __launch_bounds__(256) void prep_w(
    const float* s0, const float* s1, const float* s2, const float* s3,
    const float* s4, const float* s5, unsigned short* d0, unsigned short* d1,
    unsigned short* d2, unsigned short* d3, unsigned short* d4,
    unsigned short* d5) {
  const int seg = blockIdx.y;
  const float* src;
  unsigned short* dst;
  int N;
  bool tri;
  switch (seg) {
    case 0: src = s0; dst = d0; N = 512; tri = true; break;
    case 1: src = s1; dst = d1; N = 512; tri = true; break;
    case 2: src = s2; dst = d2; N = 512; tri = false; break;
    case 3: src = s3; dst = d3; N = 512; tri = false; break;
    case 4: src = s4; dst = d4; N = 256; tri = false; break;
    default: src = s5; dst = d5; N = 256; tri = false; break;
  }
  const int id = blockIdx.x * 256 + threadIdx.x;
  if (id >= 512 * N) return;
  const int k = id & 511;
  const int n = id >> 9;
  const float v = src[(size_t)k * N + n];
  const size_t base = (size_t)n * 512 + k;
  const size_t plane = (size_t)512 * N;
  if (tri) {
    unsigned short h, m, l;
    split3(v, h, m, l);
    dst[base] = h;
    dst[plane + base] = m;
    dst[2 * plane + base] = l;
  } else {
    unsigned short h, m;
    split2(v, h, m);
    dst[base] = h;
    dst[plane + base] = m;
  }
}

// ============ split x into 3 planes ============
__global__ __launch_bounds__(256) void split_x(const float* __restrict__ x,
                                               unsigned short* __restrict__ x3) {
  const size_t id = (size_t)blockIdx.x * 256 + threadIdx.x;
  unsigned short h, m, l;
  split3(x[id], h, m, l);
  x3[id] = h;
  x3[PLANE_XF + id] = m;
  x3[2 * PLANE_XF + id] = l;
}

// ============ GEMM-1 (split3, 6-product): x@Wm|Ws -> XMf|XSf (f32) ============
// DMA-staged (r9 pattern): LDS linear [3][rows][32el], global_load_lds,
// (row>>1)&3 slot involution.
__global__ __launch_bounds__(256) void gemm_x(
    const unsigned short* __restrict__ A3, const unsigned short* __restrict__ B30,
    const unsigned short* __restrict__ B31, float* __restrict__ C0,
    float* __restrict__ C1, const float* __restrict__ bias0,
    const float* __restrict__ bias1) {
  constexpr int BM = 128, BN = 64, K = 512;
  __shared__ __align__(16) unsigned short Asl[3][BM][32];  // 24 KiB
  __shared__ __align__(16) unsigned short Bsl[3][BN][32];  // 12 KiB
  const int tid = threadIdx.x;
  const int lane = tid & 63;
  const int wave = tid >> 6;
  const int wm = wave >> 1, wn = wave & 1;
  const int m0 = blockIdx.y * BM;
  const int n0 = blockIdx.x * BN;
  const bool str1 = (n0 >= 512);
  const int nloc = str1 ? (n0 - 512) : n0;
  const unsigned short* Bb = str1 ? B31 : B30;
  const float* bias = str1 ? bias1 : bias0;
  float* C = str1 ? C1 : C0;
  const int rl = lane & 15;
  const int kq = (lane >> 4) * 8;
  const int q = lane >> 4;
  const int kqs = kq ^ (((rl >> 1) & 3) << 3);
  const int sslot = (((lane & 3) ^ ((lane >> 3) & 3)) * 8);

  f32x4 acc[4][2];
#pragma unroll
  for (int i = 0; i < 4; ++i)
#pragma unroll
    for (int j = 0; j < 2; ++j) acc[i][j] = (f32x4){0.f, 0.f, 0.f, 0.f};

  for (int k0 = 0; k0 < K; k0 += 32) {
    // A: 24 chunks (3 planes x 8 rowblocks); B: 12 chunks (3 x 4). 1 KiB each.
#pragma unroll
    for (int it = 0; it < 9; ++it) {
      const int c = it * 4 + wave;
      if (c < 24) {
        const int plane = c >> 3;
        const int row = (c & 7) * 16 + (lane >> 2);
        gload16(&A3[(size_t)plane * PLANE_XF + (size_t)(m0 + row) * K + k0 +
                    sslot],
                &Asl[0][0][0] + c * 512);
      } else {
        const int cl = c - 24;
        const int plane = cl >> 2;
        const int row = (cl & 3) * 16 + (lane >> 2);
        gload16(&Bb[(size_t)plane * PLANE_W + (size_t)(nloc + row) * K + k0 +
                    sslot],
                &Bsl[0][0][0] + cl * 512);
      }
    }
    __syncthreads();  // drains vmcnt -> DMA landed
    bf16x8 af[4][3], bfr[2][3];
#pragma unroll
    for (int mt = 0; mt < 4; ++mt)
#pragma unroll
      for (int t = 0; t < 3; ++t)
        af[mt][t] = ldfrag(&Asl[t][wm * 64 + mt * 16 + rl][kqs]);
#pragma unroll
    for (int nt = 0; nt < 2; ++nt)
#pragma unroll
      for (int t = 0; t < 3; ++t)
        bfr[nt][t] = ldfrag(&Bsl[t][wn * 32 + nt * 16 + rl][kqs]);
#pragma unroll
    for (int mt = 0; mt < 4; ++mt)
#pragma unroll
      for (int nt = 0; nt < 2; ++nt)
        acc[mt][nt] = mfma_split6(af[mt], bfr[nt], acc[mt][nt]);
    __syncthreads();
  }
#pragma unroll
  for (int mt = 0; mt < 4; ++mt)
#pragma unroll
    for (int nt = 0; nt < 2; ++nt) {
      const int col = nloc + wn * 32 + nt * 16 + rl;
      const int row0 = m0 + wm * 64 + mt * 16 + q * 4;
      const float bv = bias[col];
#pragma unroll
      for (int r = 0; r < 4; ++r)
        C[(size_t)(row0 + r) * 512 + col] = acc[mt][nt][r] + bv;
    }
}

// ============ split2 3-product GEMM, CT-split2 output (small GEMMs) ============
// DMA-staged (r9 pattern).
template <int BM, int BN>
__global__ __launch_bounds__(256) void gemm2ct(
    const unsigned short* __restrict__ A0, const unsigned short* __restrict__ A1,
    int lda, size_t planeA, const unsigned short* __restrict__ B0,
    const unsigned short* __restrict__ B1, int ldb, size_t planeB,
    unsigned short* __restrict__ Cs0, unsigned short* __restrict__ Cs1, int ldc,
    size_t planeC, int N1, int K, const float* __restrict__ rowScale) {
  __shared__ __align__(16) unsigned short Asl[2][BM][32];
  __shared__ __align__(16) unsigned short Bsl[2][BN][32];
  const int tid = threadIdx.x;
  const int lane = tid & 63;
  const int wave = tid >> 6;
  const int wm = wave >> 1, wn = wave & 1;
  const int m0 = blockIdx.y * BM;
  const int n0 = blockIdx.x * BN;
  const bool str1 = (n0 >= N1);
  const int nloc = str1 ? (n0 - N1) : n0;
  const unsigned short* Ab = str1 ? A1 : A0;
  const unsigned short* Bb = str1 ? B1 : B0;
  const int rl = lane & 15;
  const int kq = (lane >> 4) * 8;
  const int q = lane >> 4;
  const int kqs = kq ^ (((rl >> 1) & 3) << 3);
  const int sslot = (((lane & 3) ^ ((lane >> 3) & 3)) * 8);
  constexpr int MT = BM / 32;
  constexpr int NT = BN / 32;
  constexpr int ACH = 2 * (BM / 16);
  constexpr int BCH = 2 * (BN / 16);
  constexpr int TCH = ACH + BCH;
  static_assert(TCH % 4 == 0, "chunk count must be divisible by 4 waves");

  f32x4 acc[MT][NT];
#pragma unroll
  for (int i = 0; i < MT; ++i)
#pragma unroll
    for (int j = 0; j < NT; ++j) acc[i][j] = (f32x4){0.f, 0.f, 0.f, 0.f};

  for (int k0 = 0; k0 < K; k0 += 32) {
#pragma unroll
    for (int it = 0; it < TCH / 4; ++it) {
      const int c = it * 4 + wave;
      if (c < ACH) {
        const int plane = c / (BM / 16);
        const int row = (c % (BM / 16)) * 16 + (lane >> 2);
        gload16(&Ab[(size_t)plane * planeA + (size_t)(m0 + row) * lda + k0 +
                    sslot],
                &Asl[0][0][0] + c * 512);
      } else {
        const int cl = c - ACH;
        const int plane = cl / (BN / 16);
        const int row = (cl % (BN / 16)) * 16 + (lane >> 2);
        gload16(&Bb[(size_t)plane * planeB + (size_t)(nloc + row) * ldb + k0 +
                    sslot],
                &Bsl[0][0][0] + cl * 512);
      }
    }
    __syncthreads();  // drains vmcnt -> DMA landed
    bf16x8 af[MT][2];
#pragma unroll
    for (int mt = 0; mt < MT; ++mt)
#pragma unroll
      for (int t = 0; t < 2; ++t)
        af[mt][t] = ldfrag(&Asl[t][wm * (BM / 2) + mt * 16 + rl][kqs]);
#pragma unroll
    for (int nt = 0; nt < NT; ++nt) {
      const bf16x8 b0 = ldfrag(&Bsl[0][wn * (BN / 2) + nt * 16 + rl][kqs]);
      const bf16x8 b1 = ldfrag(&Bsl[1][wn * (BN / 2) + nt * 16 + rl][kqs]);
#pragma unroll
      for (int mt = 0; mt < MT; ++mt) {
        acc[mt][nt] = mfma16(af[mt][1], b0, acc[mt][nt]);
        acc[mt][nt] = mfma16(af[mt][0], b1, acc[mt][nt]);
        acc[mt][nt] = mfma16(af[mt][0], b0, acc[mt][nt]);
      }
    }
    __syncthreads();
  }

#pragma unroll
  for (int mt = 0; mt < MT; ++mt) {
#pragma unroll
    for (int nt = 0; nt < NT; ++nt) {
      const int colL = nloc + wn * (BN / 2) + nt * 16 + rl;
      const int row0 = m0 + wm * (BM / 2) + mt * 16 + q * 4;
      float4 v4;
      float* vp = &v4.x;
#pragma unroll
      for (int r = 0; r < 4; ++r) {
        float v = acc[mt][nt][r];
        if (rowScale) v *= rowScale[row0 + r];
        vp[r] = v;
      }
      unsigned short* C = str1 ? Cs1 : Cs0;
      ushort4v h4, m4;
      split2x4(v4, h4, m4);
      const size_t base = (size_t)colL * ldc + row0;
      *(ushort4v*)(&C[base]) = h4;
      *(ushort4v*)(&C[planeC + base]) = m4;
    }
  }
}

// ============ split2 3-product GEMM, split-K, XCD-swizzled, DMA-staged =======
// m97-structure 2-barrier schedule; 0 bank conflicts (r6). ~860 TF structure
// plateau, confirmed 3x (r2/r6/r8); 8-phase alternative conclusively closed
// (r11: 0 conflicts, MfmaUtil 33%, still slower -> barrier overhead at
// 1 block/CU is structural). FROZEN.
template <int BM, int BN, int GX, int GYP, int GZ>
__global__ __launch_bounds__(256) void gemm2k(
    const unsigned short* __restrict__ A, int lda, size_t planeA,
    const unsigned short* __restrict__ B, int ldb, size_t planeB,
    float* __restrict__ Cp, int ldc, int Mtot, int Ksl) {
  static_assert(BM == 128 && BN == 128, "DMA staging assumes 128x128");
  __shared__ __align__(16) unsigned short Asl[2][BM][32];  // 16 KiB
  __shared__ __align__(16) unsigned short Bsl[2][BN][32];  // 16 KiB
  const int lin = blockIdx.x;
  const int xcd = lin & 7;
  const int s = lin >> 3;
  constexpr int per = GX * GYP;
  const int z = s / per;
  const int r = s - z * per;
  const int bx = r % GX;
  const int by = xcd * GYP + r / GX;
  const int m0 = by * BM;
  const int n0 = bx * BN;
  const int kOff = z * Ksl;

  const int tid = threadIdx.x;
  const int lane = tid & 63;
  const int wave = tid >> 6;
  const int wm = wave >> 1, wn = wave & 1;
  const int rl = lane & 15;
  const int kq = (lane >> 4) * 8;
  const int q = lane >> 4;
  const int kqs = kq ^ (((rl >> 1) & 3) << 3);
  const int sslot = (((lane & 3) ^ ((lane >> 3) & 3)) * 8);
  constexpr int MT = BM / 32;
  constexpr int NT = BN / 32;

  f32x4 acc[MT][NT];
#pragma unroll
  for (int i = 0; i < MT; ++i)
#pragma unroll
    for (int j = 0; j < NT; ++j) acc[i][j] = (f32x4){0.f, 0.f, 0.f, 0.f};

  for (int k0 = 0; k0 < Ksl; k0 += 32) {
#pragma unroll
    for (int it = 0; it < 8; ++it) {
      const int c = it * 4 + wave;
      const bool isB = c >= 16;
      const int cl = isB ? (c - 16) : c;
      const int pl = cl >> 3;
      const int row = (cl & 7) * 16 + (lane >> 2);
      const unsigned short* src =
          (isB ? B + (size_t)pl * planeB + (size_t)(n0 + row) * ldb
               : A + (size_t)pl * planeA + (size_t)(m0 + row) * lda) +
          kOff + k0 + sslot;
      unsigned short* dst =
          (isB ? &Bsl[0][0][0] : &Asl[0][0][0]) + cl * 512 + 0;
      gload16(src, dst);
    }
    __syncthreads();  // drains vmcnt -> DMA landed
    bf16x8 af[MT][2];
#pragma unroll
    for (int mt = 0; mt < MT; ++mt)
#pragma unroll
      for (int t = 0; t < 2; ++t)
        af[mt][t] = ldfrag(&Asl[t][wm * (BM / 2) + mt * 16 + rl][kqs]);
#pragma unroll
    for (int nt = 0; nt < NT; ++nt) {
      const bf16x8 b0 = ldfrag(&Bsl[0][wn * (BN / 2) + nt * 16 + rl][kqs]);
      const bf16x8 b1 = ldfrag(&Bsl[1][wn * (BN / 2) + nt * 16 + rl][kqs]);
#pragma unroll
      for (int mt = 0; mt < MT; ++mt) {
        acc[mt][nt] = mfma16(af[mt][1], b0, acc[mt][nt]);
        acc[mt][nt] = mfma16(af[mt][0], b1, acc[mt][nt]);
        acc[mt][nt] = mfma16(af[mt][0], b0, acc[mt][nt]);
      }
    }
    __syncthreads();  // protect single buffer before next DMA
  }

  const size_t zoff = (size_t)z * (size_t)Mtot * (size_t)ldc;
#pragma unroll
  for (int mt = 0; mt < MT; ++mt) {
#pragma unroll
    for (int nt = 0; nt < NT; ++nt) {
      const int colL = n0 + wn * (BN / 2) + nt * 16 + rl;
      const int row0 = m0 + wm * (BM / 2) + mt * 16 + q * 4;
#pragma unroll
      for (int r2 = 0; r2 < 4; ++r2)
        Cp[zoff + (size_t)(row0 + r2) * ldc + colL] = acc[mt][nt][r2];
    }
  }
}

// ============ row stats: XMf/XSf f32 -> M2/CS2/XM2/XS2 planes ============
__global__ __launch_bounds__(256) void row_stats(
    const float* __restrict__ XMf, const float* __restrict__ XSf,
    unsigned short* __restrict__ M2, unsigned short* __restrict__ CS2,
    unsigned short* __restrict__ XM2, unsigned short* __restrict__ XS2,
    float* __restrict__ sq, float* __restrict__ csum) {
  __shared__ float sbuf[256];
  const int i = blockIdx.x;
  const int tid = threadIdx.x;
  const size_t base = (size_t)i * kF;
  const size_t i0 = base + tid, i1 = base + tid + 256;
  const float x0 = XMf[i0], x1 = XMf[i1];
  {
    unsigned short h, m;
    split2(x0, h, m);
    XM2[i0] = h; XM2[PLANE_XF + i0] = m;
    split2(x1, h, m);
    XM2[i1] = h; XM2[PLANE_XF + i1] = m;
  }
  const float nrm = block_reduce_sum(x0 * x0 + x1 * x1, sbuf);
  const float inv = 1.0f / fmaxf(sqrtf(nrm), 1e-12f);
  const float m0 = x0 * inv, m1 = x1 * inv;
  {
    unsigned short h, m;
    split2(m0, h, m);
    M2[i0] = h; M2[PLANE_XF + i0] = m;
    split2(m1, h, m);
    M2[i1] = h; M2[PLANE_XF + i1] = m;
  }
  const float s2 = block_reduce_sum(m0 * m0 + m1 * m1, sbuf);
  if (tid == 0) sq[i] = s2;

  const float y0 = XSf[i0], y1 = XSf[i1];
  {
    unsigned short h, m;
    split2(y0, h, m);
    XS2[i0] = h; XS2[PLANE_XF + i0] = m;
    split2(y1, h, m);
    XS2[i1] = h; XS2[PLANE_XF + i1] = m;
  }
  const float e0 = expf(y0), e1 = expf(y1);
  const float nrm2 = block_reduce_sum(e0 * e0 + e1 * e1, sbuf);
  const float inv2 = 1.0f / fmaxf(sqrtf(nrm2), 1e-12f);
  const float c0 = e0 * inv2, c1 = e1 * inv2;
  const float sc = block_reduce_sum(c0 + c1, sbuf);
  if (tid == 0) csum[i] = sc;
  {
    unsigned short h, m;
    split2(sqrtf(c0), h, m);
    CS2[i0] = h; CS2[PLANE_XF + i0] = m;
    split2(sqrtf(c1), h, m);
    CS2[i1] = h; CS2[PLANE_XF + i1] = m;
  }
}

// ============ symmetric dual NT-GEMM (split2, 3-prod): ws_raw = exp(-res) ====
// 128x128 tri-tiles, DMA-staged, 64 KiB LDS (2 blocks/CU). Frozen (r9 win).
__global__ __launch_bounds__(256, 2) void ws_mfma2(
    const unsigned short* __restrict__ M2, const unsigned short* __restrict__ CS2,
    const float* __restrict__ sq, const float* __restrict__ csum,
    float* __restrict__ WSR) {
  __shared__ __align__(16) unsigned short S[4][2][128][32];  // 64 KiB
  int bi, bj;
  tri_map(blockIdx.x, bi, bj);
  const int i0 = bi * 128, j0 = bj * 128;
  const int tid = threadIdx.x;
  const int lane = tid & 63;
  const int wave = tid >> 6;
  const int wm = wave >> 1, wn = wave & 1;
  const int rl = lane & 15;
  const int kq = (lane >> 4) * 8;
  const int q = lane >> 4;
  const int kqs = kq ^ (((rl >> 1) & 3) << 3);
  const int sslot = (((lane & 3) ^ ((lane >> 3) & 3)) * 8);

  f32x4 aM[4][4], aC[4][4];
#pragma unroll
  for (int i = 0; i < 4; ++i)
#pragma unroll
    for (int j = 0; j < 4; ++j) {
      aM[i][j] = (f32x4){0.f, 0.f, 0.f, 0.f};
      aC[i][j] = (f32x4){0.f, 0.f, 0.f, 0.f};
    }

  for (int k0 = 0; k0 < kF; k0 += 32) {
#pragma unroll
    for (int it = 0; it < 16; ++it) {
      const int c = it * 4 + wave;
      const int op = c >> 4;
      const int plane = (c >> 3) & 1;
      const int row = (c & 7) * 16 + (lane >> 2);
      const unsigned short* mat = (op & 1) ? CS2 : M2;
      const int rowoff = (op < 2) ? i0 : j0;
      const unsigned short* src = mat + (size_t)plane * PLANE_XF +
                                  (size_t)(rowoff + row) * kF + k0 + sslot;
      unsigned short* dst = &S[0][0][0][0] + c * 512;
      gload16(src, dst);
    }
    __syncthreads();  // drains vmcnt -> DMA landed
    bf16x8 am[4][2], ac[4][2];
#pragma unroll
    for (int mt = 0; mt < 4; ++mt)
#pragma unroll
      for (int t = 0; t < 2; ++t) {
        am[mt][t] = ldfrag(&S[0][t][wm * 64 + mt * 16 + rl][kqs]);
        ac[mt][t] = ldfrag(&S[1][t][wm * 64 + mt * 16 + rl][kqs]);
      }
#pragma unroll
    for (int nt = 0; nt < 4; ++nt) {
      const bf16x8 bm0 = ldfrag(&S[2][0][wn * 64 + nt * 16 + rl][kqs]);
      const bf16x8 bm1 = ldfrag(&S[2][1][wn * 64 + nt * 16 + rl][kqs]);
      const bf16x8 bc0 = ldfrag(&S[3][0][wn * 64 + nt * 16 + rl][kqs]);
      const bf16x8 bc1 = ldfrag(&S[3][1][wn * 64 + nt * 16 + rl][kqs]);
#pragma unroll
      for (int mt = 0; mt < 4; ++mt) {
        aM[mt][nt] = mfma16(am[mt][1], bm0, aM[mt][nt]);
        aM[mt][nt] = mfma16(am[mt][0], bm1, aM[mt][nt]);
        aM[mt][nt] = mfma16(am[mt][0], bm0, aM[mt][nt]);
        aC[mt][nt] = mfma16(ac[mt][1], bc0, aC[mt][nt]);
        aC[mt][nt] = mfma16(ac[mt][0], bc1, aC[mt][nt]);
        aC[mt][nt] = mfma16(ac[mt][0], bc0, aC[mt][nt]);
      }
    }
    __syncthreads();
  }

#pragma unroll
  for (int mt = 0; mt < 4; ++mt) {
#pragma unroll
    for (int nt = 0; nt < 4; ++nt) {
      const int j = j0 + wn * 64 + nt * 16 + rl;
      const int ib = i0 + wm * 64 + mt * 16 + q * 4;
      const float sqj = sq[j], csj = csum[j];
      float4 vv;
      float* vp = &vv.x;
#pragma unroll
      for (int r = 0; r < 4; ++r) {
        const int i = ib + r;
        const float d2 = fmaxf(sq[i] + sqj - 2.0f * aM[mt][nt][r], 0.0f);
        const float res = d2 + csum[i] + csj - 2.0f * aC[mt][nt][r];
        const float v = expf(-res);
        vp[r] = v;
        WSR[(size_t)i * kN + j] = v;
      }
      if (bi != bj) *(float4*)(&WSR[(size_t)j * kN + ib]) = vv;
    }
  }
}

// ============ row inverse L2 norm of WSR ============
__global__ __launch_bounds__(256) void row_invnorm_kernel(
    const float* __restrict__ WSR, float* __restrict__ invn) {
  __shared__ float sbuf[256];
  const int i = blockIdx.x;
  const int tid = threadIdx.x;
  const float4* rp = (const float4*)(WSR + (size_t)i * kN);
  float s = 0.0f;
#pragma unroll
  for (int q = 0; q < (kN / 4) / 256; ++q) {
    const float4 v = rp[tid + q * 256];
    s += v.x * v.x + v.y * v.y + v.z * v.z + v.w * v.w;
  }
  s = block_reduce_sum(s, sbuf);
  if (tid == 0) invn[i] = 1.0f / fmaxf(sqrtf(s), 1e-12f);
}

// ============ adjacency transform + transposed 2-plane split + deg ============
// Algebraic identity (r8): sigmoid(logit(t)+logit(e)) == t*e/(t*e+(1-t)(1-e));
// adj is memory-bound (r8 measured).
__device__ __forceinline__ float adj_val(float w, float inv, float nev, float ev,
                                         float b, float d, bool diag) {
  float t = (1.0f - b) * (w * inv) + b * nev;
  t = fminf(fmaxf(t, kClamp), 1.0f - kClamp);
  const float e = fminf(fmaxf(ev, kClamp), 1.0f - kClamp);
  const float num = t * e;
  const float den = num + (1.0f - t) * (1.0f - e);
  const float s = num / den;
  float v = (s > d) ? s : 0.0f;
  if (diag) v = (v > 0.0f) ? v : 1.0f;
  return v;
}

__global__ __launch_bounds__(256) void adj_transpose(
    const float* __restrict__ WSR, const float* __restrict__ invn,
    const float* __restrict__ ne, const float* __restrict__ epsm,
    const float* __restrict__ beta_p, const float* __restrict__ delta_p,
    unsigned short* __restrict__ Adj2, float* __restrict__ degp) {
  __shared__ float T0[64][65];
  __shared__ float T1[64][65];
  const float b = beta_p[0];
  const float d = delta_p[0];
  int bi, bj;
  tri_map(blockIdx.x, bi, bj);
  const int i0 = bi * 64, j0 = bj * 64;
  const int tid = threadIdx.x;
  const int rlq = tid >> 4;
  const int cq = (tid & 15) * 4;
#pragma unroll
  for (int p = 0; p < 4; ++p) {
    const int ii = p * 16 + rlq;
    {
      const size_t off = (size_t)(i0 + ii) * kN + j0 + cq;
      const float4 w4 = *(const float4*)(&WSR[off]);
      const float4 n4 = *(const float4*)(&ne[off]);
      const float4 e4 = *(const float4*)(&epsm[off]);
      const float inv = invn[i0 + ii];
      const float wv[4] = {w4.x, w4.y, w4.z, w4.w};
      const float nv[4] = {n4.x, n4.y, n4.z, n4.w};
      const float ev[4] = {e4.x, e4.y, e4.z, e4.w};
#pragma unroll
      for (int u = 0; u < 4; ++u)
        T0[ii][cq + u] =
            adj_val(wv[u], inv, nv[u], ev[u], b, d, (i0 + ii) == (j0 + cq + u));
    }
    if (bi != bj) {
      const size_t off = (size_t)(j0 + ii) * kN + i0 + cq;
      const float4 w4 = *(const float4*)(&WSR[off]);
      const float4 n4 = *(const float4*)(&ne[off]);
      const float4 e4 = *(const float4*)(&epsm[off]);
      const float inv = invn[j0 + ii];
      const float wv[4] = {w4.x, w4.y, w4.z, w4.w};
      const float nv[4] = {n4.x, n4.y, n4.z, n4.w};
      const float ev[4] = {e4.x, e4.y, e4.z, e4.w};
#pragma unroll
      for (int u = 0; u < 4; ++u)
        T1[ii][cq + u] = adj_val(wv[u], inv, nv[u], ev[u], b, d, false);
    }
  }
  __syncthreads();
#pragma unroll
  for (int p = 0; p < 4; ++p) {
    const int jj = p * 16 + rlq;
    {
      const float4 v4 = make_float4(T0[cq + 0][jj], T0[cq + 1][jj],
                                    T0[cq + 2][jj], T0[cq + 3][jj]);
      ushort4v h4, m4;
      split2x4(v4, h4, m4);
      const size_t base = (size_t)(j0 + jj) * kN + i0 + cq;
      *(ushort4v*)(&Adj2[base]) = h4;
      *(ushort4v*)(&Adj2[PLANE_NN + base]) = m4;
    }
    if (bi != bj) {
      const float4 v4 = make_float4(T1[cq + 0][jj], T1[cq + 1][jj],
                                    T1[cq + 2][jj], T1[cq + 3][jj]);
      ushort4v h4, m4;
      split2x4(v4, h4, m4);
      const size_t base = (size_t)(i0 + jj) * kN + j0 + cq;
      *(ushort4v*)(&Adj2[base]) = h4;
      *(ushort4v*)(&Adj2[PLANE_NN + base]) = m4;
    }
  }
  if (tid < 64) {
    float s = 0.0f;
#pragma unroll 8
    for (int ii = 0; ii < 64; ++ii) s += T0[ii][tid];
    degp[(size_t)bi * kN + j0 + tid] = s;
    if (bi != bj) {
      float s1 = 0.0f;
#pragma unroll 8
      for (int ii = 0; ii < 64; ++ii) s1 += T1[ii][tid];
      degp[(size_t)bj * kN + i0 + tid] = s1;
    }
  }
}

__global__ __launch_bounds__(256) void deg_dis_kernel(
    const float* __restrict__ degp, float* __restrict__ dis) {
  const int j = blockIdx.x * 256 + threadIdx.x;
  float s = 0.0f;
#pragma unroll
  for (int c = 0; c < 64; ++c) s += degp[(size_t)c * kN + j];
  dis[j] = (s > 0.0f) ? (1.0f / sqrtf(s)) : 0.0f;
}

// ============ split-K combines ============
__global__ __launch_bounds__(256) void combine_h(
    const float* __restrict__ hp, const float* __restrict__ dis,
    const float* __restrict__ b0, const float* __restrict__ b1,
    unsigned short* __restrict__ h2) {
  const size_t qd = (size_t)blockIdx.x * 256 + threadIdx.x;
  const int m = (int)(qd >> 8);
  const int c0 = (int)(qd & 255) * 4;
  const size_t off = (size_t)m * 1024 + c0;
  const float4 s0 = *(const float4*)(&hp[off]);
  const float4 s1 = *(const float4*)(&hp[PLANE_H + off]);
  const float4 s2 = *(const float4*)(&hp[2 * PLANE_H + off]);
  const float4 s3 = *(const float4*)(&hp[3 * PLANE_H + off]);
  const float4 bv = (c0 < 512) ? *(const float4*)(&b0[c0])
                               : *(const float4*)(&b1[c0 - 512]);
  const float ds = dis[m];
  float4 v4;
  v4.x = fmaxf(ds * (s0.x + s1.x + s2.x + s3.x) + bv.x, 0.f);
  v4.y = fmaxf(ds * (s0.y + s1.y + s2.y + s3.y) + bv.y, 0.f);
  v4.z = fmaxf(ds * (s0.z + s1.z + s2.z + s3.z) + bv.z, 0.f);
  v4.w = fmaxf(ds * (s0.w + s1.w + s2.w + s3.w) + bv.w, 0.f);
  ushort4v h4, m4;
  split2x4(v4, h4, m4);
  *(ushort4v*)(&h2[off]) = h4;
  *(ushort4v*)(&h2[PLANE_H + off]) = m4;
}

__global__ __launch_bounds__(256) void combine_z(
    const float* __restrict__ zp, const float* __restrict__ dis,
    const float* __restrict__ b0, const float* __restrict__ b1,
    float* __restrict__ out) {
  const size_t qd = (size_t)blockIdx.x * 256 + threadIdx.x;
  const int m = (int)(qd >> 7);
  const int c0 = (int)(qd & 127) * 4;
  const size_t off = (size_t)m * 512 + c0;
  constexpr size_t PZ = (size_t)kN * 512;
  const float4 s0 = *(const float4*)(&zp[off]);
  const float4 s1 = *(const float4*)(&zp[PZ + off]);
  const float4 s2 = *(const float4*)(&zp[2 * PZ + off]);
  const float4 s3 = *(const float4*)(&zp[3 * PZ + off]);
  const float4 bv = (c0 < 256) ? *(const float4*)(&b0[c0])
                               : *(const float4*)(&b1[c0 - 256]);
  const float ds = dis[m];
  float4 v4;
  v4.x = fmaxf(ds * (s0.x + s1.x + s2.x + s3.x) + bv.x, 0.f);
  v4.y = fmaxf(ds * (s0.y + s1.y + s2.y + s3.y) + bv.y, 0.f);
  v4.z = fmaxf(ds * (s0.z + s1.z + s2.z + s3.z) + bv.z, 0.f);
  v4.w = fmaxf(ds * (s0.w + s1.w + s2.w + s3.w) + bv.w, 0.f);
  float* dst = (c0 < 256) ? &out[(size_t)m * 256 + c0]
                          : &out[(size_t)kN * 256 + (size_t)m * 256 + (c0 - 256)];
  *(float4*)dst = v4;
}

// ============ launch ============
extern "C" void kernel_launch(void* const* d_in, const int* in_sizes, int n_in,
                              void* d_out, int out_size, void* d_ws,
                              size_t ws_size, hipStream_t stream) {
  const float* x = (const float*)d_in[0];
  const float* ne = (const float*)d_in[1];
  const float* beta = (const float*)d_in[2];
  const float* delta = (const float*)d_in[3];
  const float* epsm = (const float*)d_in[4];
  const float* Wm = (const float*)d_in[5];
  const float* bm = (const float*)d_in[6];
  const float* Ws = (const float*)d_in[7];
  const float* bs = (const float*)d_in[8];
  const float* mW0 = (const float*)d_in[9];
  const float* mb0 = (const float*)d_in[10];
  const float* mW1 = (const float*)d_in[11];
  const float* mb1 = (const float*)d_in[12];
  const float* sW0 = (const float*)d_in[13];
  const float* sb0 = (const float*)d_in[14];
  const float* sW1 = (const float*)d_in[15];
  const float* sb1 = (const float*)d_in[16];
  float* out = (float*)d_out;

  // WSR (67.1 MB) is dead after adj_transpose; hp/zp (<= 67.1 MB) alias it.
  char* p = (char*)d_ws;
  float* WSR = (float*)p;                     p += PLANE_NN * 4;
  unsigned short* Adj2 = (unsigned short*)p;  p += 2 * PLANE_NN * 2;
  unsigned short* x3 = (unsigned short*)p;    p += 3 * PLANE_XF * 2;  // -> V1t2
  float* XMf = (float*)p;                     p += PLANE_XF * 4;
  float* XSf = (float*)p;                     p += PLANE_XF * 4;
  unsigned short* XM2 = (unsigned short*)p;   p += 2 * PLANE_XF * 2;  // -> h2
  unsigned short* XS2 = (unsigned short*)p;   p += 2 * PLANE_XF * 2;
  unsigned short* M2 = (unsigned short*)p;    p += 2 * PLANE_XF * 2;  // -> V0t2
  unsigned short* CS2 = (unsigned short*)p;   p += 2 * PLANE_XF * 2;
  unsigned short* Wm3 = (unsigned short*)p;   p += 3 * PLANE_W * 2;
  unsigned short* Ws3 = (unsigned short*)p;   p += 3 * PLANE_W * 2;
  unsigned short* mW0t2 = (unsigned short*)p; p += 2 * PLANE_W * 2;
  unsigned short* sW0t2 = (unsigned short*)p; p += 2 * PLANE_W * 2;
  unsigned short* mW1t2 = (unsigned short*)p; p += 2 * PLANE_W1 * 2;
  unsigned short* sW1t2 = (unsigned short*)p; p += 2 * PLANE_W1 * 2;
  float* degp = (float*)p;                    p += (size_t)64 * kN * 4;
  float* sq = (float*)p;                      p += kN * 4;
  float* csum = (float*)p;                    p += kN * 4;
  float* invn = (float*)p;                    p += kN * 4;
  float* dis = (float*)p;                     p += kN * 4;

  float* hp = WSR;   // 4 * PLANE_H floats = PLANE_NN floats exactly
  float* zp = WSR;   // 4 * kN*512 floats = PLANE_NN/2 floats
  unsigned short* V1t2 = x3;
  unsigned short* h2 = XM2;
  unsigned short* V0t2 = M2;

  const dim3 blk(256);
  const int nTri = (kN / 64) * (kN / 64 + 1) / 2;       // 2080 (64-tiles)
  const int nTri128 = (kN / 128) * (kN / 128 + 1) / 2;  // 528 (128-tiles)

  prep_w<<<dim3(1024, 6), blk, 0, stream>>>(Wm, Ws, mW0, sW0, mW1, sW1, Wm3,
                                            Ws3, mW0t2, sW0t2, mW1t2, sW1t2);
  split_x<<<(kN * kF) / 256, blk, 0, stream>>>(x, x3);

  // 1) x_mean/x_std (split3, full precision) -> f32, DMA-staged
  gemm_x<<<dim3(16, 32), blk, 0, stream>>>(x3, Wm3, Ws3, XMf, XSf, bm, bs);

  // 2) row stats + all split2 planes
  row_stats<<<kN, blk, 0, stream>>>(XMf, XSf, M2, CS2, XM2, XS2, sq, csum);

  // 3) ws_raw (triangle + mirror), 128x128 DMA-staged tiles
  ws_mfma2<<<nTri128, blk, 0, stream>>>(M2, CS2, sq, csum, WSR);

  // 4) row inverse norms
  row_invnorm_kernel<<<kN, blk, 0, stream>>>(WSR, invn);

  // 5) adjacency -> Adj2 (transposed 2-plane) + deg partials. WSR dead after.
  adj_transpose<<<nTri, blk, 0, stream>>>(WSR, invn, ne, epsm, beta, delta,
                                          Adj2, degp);
  deg_dis_kernel<<<kN / 256, blk, 0, stream>>>(degp, dis);

  // 6) V0t = (dis_i * XM@W0 | XS@W0)^T  -> split2 CT planes [1024][4096]
  gemm2ct<128, 64><<<dim3(16, 32), blk, 0, stream>>>(
      XM2, XS2, kF, PLANE_XF, mW0t2, sW0t2, kF, PLANE_W, V0t2,
      V0t2 + (size_t)512 * kN, kN, PLANE_V0, 512, kF, dis);

  // 7) h partials: AdjT @ V0t, split-K=4, XCD-swizzled (8*8*4*4 = 1024 blocks)
  gemm2k<128, 128, 8, 4, 4><<<1024, blk, 0, stream>>>(
      Adj2, kN, PLANE_NN, V0t2, kN, PLANE_V0, hp, 1024, kN, kN / 4);
  combine_h<<<(int)(PLANE_H / 4 / 256), blk, 0, stream>>>(hp, dis, mb0, sb0, h2);

  // 8) V1t = (dis_i * h@W1)^T -> split2 CT planes [512][4096]
  gemm2ct<64, 64><<<dim3(8, 64), blk, 0, stream>>>(
      h2, h2 + 512, 1024, PLANE_H, mW1t2, sW1t2, kF, PLANE_W1, V1t2,
      V1t2 + (size_t)256 * kN, kN, PLANE_V1, 256, kF, dis);

  // 9) z partials: AdjT @ V1t, split-K=4, XCD-swizzled (8*4*4*4 = 512 blocks)
  gemm2k<128, 128, 4, 4, 4><<<512, blk, 0, stream>>>(
      Adj2, kN, PLANE_NN, V1t2, kN, PLANE_V1, zp, 512, kN, kN / 4);
  combine_z<<<(int)((size_t)kN * 512 / 4 / 256), blk, 0, stream>>>(zp, dis, mb1,
                                                                   sb1, out);
}